// Round 16
// baseline (653.070 us; speedup 1.0000x reference)
//
#include <hip/hip_runtime.h>

typedef unsigned short u16;
typedef unsigned char u8;
typedef unsigned int u32;
typedef __bf16 bf16x8 __attribute__((ext_vector_type(8)));
typedef float f32x4 __attribute__((ext_vector_type(4)));
typedef u32 u32x4 __attribute__((ext_vector_type(4)));
typedef u16 u16x4 __attribute__((ext_vector_type(4)));
typedef int i32x4 __attribute__((ext_vector_type(4)));

#define NH 2048
#define BATCH 256
#define NIN 1024
#define NOUT 256
#define LAY 4
#define TSS 32
#define BK 64

#define SW_W 5747.0f  // 127 / (1/sqrt(2048)); |W|<0.0220971 -> |W*SW_W|<127.002
#define INV_DQ (1.0f / (127.0f * 5747.0f))

#define WAITVM(N) asm volatile("s_waitcnt vmcnt(" #N ")" ::: "memory")

__device__ __forceinline__ u16 f2bf(float f) {
  u32 u = __builtin_bit_cast(u32, f);
  u = (u + 0x7FFFu + ((u >> 16) & 1u)) >> 16;
  return (u16)u;
}
__device__ __forceinline__ float bf2f(u16 h) {
  u32 u = ((u32)h) << 16;
  return __builtin_bit_cast(float, u);
}

// sin for |x| <= ~6, abs err < ~4e-6 (degree-9 odd, pi range reduction)
__device__ __forceinline__ float fast_sin(float x) {
  float k = __builtin_rintf(x * 0.3183098861837907f);
  float r = __builtin_fmaf(k, -3.14159274101257324f, x);
  r = __builtin_fmaf(k, 8.742277657347586e-08f, r);
  float s = r * r;
  float p = __builtin_fmaf(s, 2.75573192e-06f, -1.98412698e-04f);
  p = __builtin_fmaf(s, p, 8.33333333e-03f);
  p = __builtin_fmaf(s, p, -1.66666667e-01f);
  p = r + r * s * p;
  int ki = (int)k;
  return (ki & 1) ? -p : p;
}

__device__ __forceinline__ bf16x8 ld_frag(const u16* p) {
  u32x4 r = *(const u32x4*)p;
  return __builtin_bit_cast(bf16x8, r);
}

__device__ __forceinline__ f32x4 mfma16(bf16x8 a, bf16x8 b, f32x4 c) {
  return __builtin_amdgcn_mfma_f32_16x16x32_bf16(a, b, c, 0, 0, 0);
}

// i8 MFMA via the documented gfx950 builtin (compiler handles all hazards)
__device__ __forceinline__ i32x4 mfma_i8(i32x4 a, i32x4 b, i32x4 c) {
  return __builtin_amdgcn_mfma_i32_16x16x64_i8(a, b, c, 0, 0, 0);
}

__device__ __forceinline__ void gload16(const void* g, void* lds) {
  __builtin_amdgcn_global_load_lds(
      (__attribute__((address_space(1))) u32*)g,
      (__attribute__((address_space(3))) u32*)lds, 16, 0, 0);
}

// ---------------- pack / convert kernels ----------------

// W fp32 -> i8 (scale SW_W), 4 elems/thread
__global__ __launch_bounds__(256) void k_cvt_w8(const float* __restrict__ in,
                                                u32* __restrict__ out, int n4) {
  int i = blockIdx.x * 256 + threadIdx.x;
  if (i >= n4) return;
  f32x4 v = ((const f32x4*)in)[i];
  u32 o = 0;
  #pragma unroll
  for (int j = 0; j < 4; j++) {
    int q = (int)__builtin_rintf(v[j] * SW_W);
    o |= ((u32)(q & 255)) << (8 * j);
  }
  out[i] = o;
}

__global__ __launch_bounds__(256) void k_split2(const float* __restrict__ in,
                                                u16* __restrict__ hi,
                                                u16* __restrict__ lo, int n4) {
  int i = blockIdx.x * 256 + threadIdx.x;
  if (i >= n4) return;
  f32x4 v = ((const f32x4*)in)[i];
  u16x4 hv, lv;
  #pragma unroll
  for (int j = 0; j < 4; j++) {
    u16 h = f2bf(v[j]);
    hv[j] = h;
    lv[j] = f2bf(v[j] - bf2f(h));
  }
  ((u16x4*)hi)[i] = hv;
  ((u16x4*)lo)[i] = lv;
}

// ---------------- bf16 GEMM (r5-proven 2-phase structure; x_in path) --------

struct GemmArgs {
  const u16* A[4];
  const u16* B[4];
  void* G;
  int ldA, ldB, kiters, nl;
};

template <int OBF, int NKS>
__global__ __launch_bounds__(256, 2) void k_gemm(GemmArgs args) {
  __shared__ alignas(16) u16 Ab[2][128 * BK];
  __shared__ alignas(16) u16 Bb[2][128 * BK];

  int bid = blockIdx.x;
  int nl = args.nl;
  int l = bid % nl;
  int t1 = bid / nl;
  int ks = t1 & (NKS - 1);
  int t2 = t1 / NKS;
  int nt = t2 & 15;
  int mt = t2 >> 4;

  int tid = threadIdx.x;
  int w = tid >> 6, lane = tid & 63;
  int l15 = lane & 15, l4 = lane >> 4;
  int ldA = args.ldA, ldB = args.ldB;
  int kiters = args.kiters;

  const u16* Ag = args.A[l] + (size_t)(mt * 128) * ldA + ks * (kiters * BK);
  const u16* Bg = args.B[l] + (size_t)(nt * 128) * ldB + ks * (kiters * BK);

  int srow = w * 32 + (lane >> 3);
  int csrc = ((lane & 7) ^ (lane >> 3)) * 8;
  int agoff[4], bgoff[4], lbase[4];
  #pragma unroll
  for (int j = 0; j < 4; j++) {
    agoff[j] = (srow + j * 8) * ldA + csrc;
    bgoff[j] = (srow + j * 8) * ldB + csrc;
    lbase[j] = w * 2048 + j * 512;
  }

  int wr = w >> 1, wc = w & 1;

  f32x4 zero = {0.f, 0.f, 0.f, 0.f};
  f32x4 acc[4][4];
  #pragma unroll
  for (int m = 0; m < 4; m++)
    #pragma unroll
    for (int n = 0; n < 4; n++) acc[m][n] = zero;

  auto stage = [&](int bufi, int kb) {
    int k0 = kb * BK;
    #pragma unroll
    for (int j = 0; j < 4; j++) {
      gload16(Ag + agoff[j] + k0, &Ab[bufi][lbase[j]]);
      gload16(Bg + bgoff[j] + k0, &Bb[bufi][lbase[j]]);
    }
  };
  auto compute = [&](int bufi) {
    #pragma unroll
    for (int kk = 0; kk < 2; kk++) {
      int swz = ((kk * 4 + l4) ^ (l15 & 7)) * 8;
      bf16x8 a[4], b[4];
      #pragma unroll
      for (int m = 0; m < 4; m++)
        a[m] = ld_frag(&Ab[bufi][(wr * 64 + m * 16 + l15) * BK + swz]);
      #pragma unroll
      for (int n = 0; n < 4; n++)
        b[n] = ld_frag(&Bb[bufi][(wc * 64 + n * 16 + l15) * BK + swz]);
      #pragma unroll
      for (int m = 0; m < 4; m++)
        #pragma unroll
        for (int n = 0; n < 4; n++)
          acc[m][n] = mfma16(a[m], b[n], acc[m][n]);
    }
  };

  stage(0, 0);
  stage(1, 1);

  int cur = 0;
  for (int kb = 0; kb < kiters - 2; kb++) {
    WAITVM(8);
    __builtin_amdgcn_s_barrier();
    compute(cur);
    __builtin_amdgcn_s_barrier();
    stage(cur, kb + 2);
    cur ^= 1;
  }
  WAITVM(8);
  __builtin_amdgcn_s_barrier();
  compute(cur);
  cur ^= 1;
  WAITVM(0);
  __builtin_amdgcn_s_barrier();
  compute(cur);

  size_t obase = ((size_t)(ks * nl + l) * BATCH + mt * 128) * NH + nt * 128;
  if (OBF) {
    u16* Go = (u16*)args.G + obase;
    #pragma unroll
    for (int m = 0; m < 4; m++) {
      int row = wr * 64 + m * 16 + l4 * 4;
      #pragma unroll
      for (int n = 0; n < 4; n++) {
        int col = wc * 64 + n * 16 + l15;
        #pragma unroll
        for (int r = 0; r < 4; r++)
          Go[(size_t)(row + r) * NH + col] = f2bf(acc[m][n][r]);
      }
    }
  } else {
    float* Go = (float*)args.G + obase;
    #pragma unroll
    for (int m = 0; m < 4; m++) {
      int row = wr * 64 + m * 16 + l4 * 4;
      #pragma unroll
      for (int n = 0; n < 4; n++) {
        int col = wc * 64 + n * 16 + l15;
        #pragma unroll
        for (int r = 0; r < 4; r++)
          Go[(size_t)(row + r) * NH + col] = acc[m][n][r];
      }
    }
  }
}

// ---------------- fused step kernel: 4-layer GEMM + in-register chain -------
// Block tile: 32 rows x 64 cols x ALL 4 LAYERS. The layer recurrence
// new_h[l] = sin(new_h[l-1] + G[l] + b[l]) is ELEMENT-LOCAL once all 4 G
// values for a position are in registers -> G never touches memory, and one
// kernel per step replaces gemm+chain (launch count halves).
// One K=2048 loop (kiters=16, BK=128 i8) stages A[4 layers]+B[4 layers] per
// buffer: 12 gloads -> WAITVM(12). LDS 96 KB (1 block/CU, 4 waves).
// Swizzle/schedule identical to the r13-15-proven pattern.
// Wave tile 16x32: wr=w&1 (row half), wc=w>>1 (col half); acc[4][2].
// Decode: nt8=bid&7, mt=(bid>>3)&7, ntl=bid>>6; nt=nt8*4+ntl. bid%8=nt8 ->
// each XCD's L2 holds W cols [nt8*256,+256) x 4 layers (2 MB) + full h (2 MB).

struct StepArgs {
  const u8* hin;   // [LAY][BATCH][NH] i8
  const u8* W8;    // [LAY][NH][NH] i8
  u8* hout;        // [LAY][BATCH][NH] i8
  u16* h3bf;       // [BATCH][NH] bf16 (layer-3 copy)
  const float* xin;
  const float* brec;
};

__global__ __launch_bounds__(256, 1) void k_step(StepArgs args) {
  __shared__ alignas(16) u8 Ab[2][LAY][32 * 128];  // 32 KB
  __shared__ alignas(16) u8 Bb[2][LAY][64 * 128];  // 64 KB

  int bid = blockIdx.x;
  int nt8 = bid & 7;
  int mt = (bid >> 3) & 7;
  int ntl = bid >> 6;
  int nt = nt8 * 4 + ntl;

  int tid = threadIdx.x;
  int lane = tid & 63;
  int w = tid >> 6;
  int l15 = lane & 15, l4 = lane >> 4;
  int wr = w & 1, wc = w >> 1;  // wave tile 16x32

  // staging map (proven): LDS byte L = tid*16 within a [rows][128] tile ->
  // row = tid>>3, chunkpos = tid&7; inverse-swizzled src chunk = pos^(row&7).
  int srow = tid >> 3;
  int csrc = ((tid & 7) ^ (srow & 7)) * 16;  // bytes

  const u8* Ag[LAY];
  const u8* Bg[LAY];
  #pragma unroll
  for (int l = 0; l < LAY; l++) {
    Ag[l] = args.hin + (size_t)l * (BATCH * NH) + (size_t)(mt * 32) * NH;
    Bg[l] = args.W8 + (size_t)l * (NH * NH) + (size_t)(nt * 64) * NH;
  }

  i32x4 zero = {0, 0, 0, 0};
  i32x4 acc[LAY][2];
  #pragma unroll
  for (int l = 0; l < LAY; l++) {
    acc[l][0] = zero;
    acc[l][1] = zero;
  }

  auto stage = [&](int bufi, int kb) {
    int k0 = kb * 128;
    #pragma unroll
    for (int l = 0; l < LAY; l++)
      gload16(Ag[l] + srow * NH + csrc + k0, &Ab[bufi][l][tid * 16]);
    #pragma unroll
    for (int l = 0; l < LAY; l++)
      #pragma unroll
      for (int j = 0; j < 2; j++)
        gload16(Bg[l] + (size_t)(j * 32 + srow) * NH + csrc + k0,
                &Bb[bufi][l][j * 4096 + tid * 16]);
  };
  auto compute = [&](int bufi) {
    #pragma unroll
    for (int kk = 0; kk < 2; kk++) {
      int swz = ((kk * 4 + l4) ^ (l15 & 7)) * 16;  // bytes
      #pragma unroll
      for (int l = 0; l < LAY; l++) {
        i32x4 a = *(const i32x4*)&Ab[bufi][l][(wr * 16 + l15) * 128 + swz];
        i32x4 b0 = *(const i32x4*)&Bb[bufi][l][(wc * 32 + l15) * 128 + swz];
        i32x4 b1 = *(const i32x4*)&Bb[bufi][l][(wc * 32 + 16 + l15) * 128 + swz];
        acc[l][0] = mfma_i8(a, b0, acc[l][0]);
        acc[l][1] = mfma_i8(a, b1, acc[l][1]);
      }
    }
  };

  stage(0, 0);
  stage(1, 1);

  int cur = 0;
  #pragma unroll 1
  for (int kb = 0; kb < 14; kb++) {  // kiters = 16
    WAITVM(12);
    __builtin_amdgcn_s_barrier();
    compute(cur);
    __builtin_amdgcn_s_barrier();
    stage(cur, kb + 2);
    cur ^= 1;
  }
  WAITVM(12);
  __builtin_amdgcn_s_barrier();
  compute(cur);
  cur ^= 1;
  WAITVM(0);
  __builtin_amdgcn_s_barrier();
  compute(cur);

  // ---- in-register chain (dequant in fp32; no G round-trip) ----
  // lane positions: row = mt*32 + wr*16 + l4*4 + r, col = nt*64 + wc*32 + n*16 + l15
  #pragma unroll
  for (int n = 0; n < 2; n++) {
    int col = nt * 64 + wc * 32 + n * 16 + l15;
    float bb[LAY];
    #pragma unroll
    for (int l = 0; l < LAY; l++) bb[l] = args.brec[l * NH + col];
    #pragma unroll
    for (int r = 0; r < 4; r++) {
      int row = mt * 32 + wr * 16 + l4 * 4 + r;
      size_t base = (size_t)row * NH + col;
      float pre = args.xin[base];
      #pragma unroll
      for (int l = 0; l < LAY; l++) {
        float g = (float)acc[l][n][r] * INV_DQ;
        float v = fast_sin(pre + g + bb[l]);
        pre = v;
        int q = (int)__builtin_rintf(v * 127.0f);
        args.hout[(size_t)l * (BATCH * NH) + base] = (u8)(q & 255);
        if (l == LAY - 1) args.h3bf[base] = f2bf(v);
      }
    }
  }
}

// x_in = sum of 6 partial slices + bias (fp32 partials)
__global__ __launch_bounds__(256) void k_xin_fin(const float* __restrict__ Gp2,
                                                 const float* __restrict__ bin,
                                                 float* __restrict__ x_in) {
  int i = blockIdx.x * 256 + threadIdx.x;
  int e = i * 4;
  int col = e & (NH - 1);
  f32x4 s = *(const f32x4*)(bin + col);
  #pragma unroll
  for (int t = 0; t < 6; t++)
    s += *(const f32x4*)(Gp2 + (size_t)t * (BATCH * NH) + e);
  *(f32x4*)(x_in + e) = s;
}

// ---------------- output projection: out = h3 @ (Wh+Wl)^T + b ----------------
__global__ __launch_bounds__(64) void k_gemm_out(const u16* __restrict__ h3,
                                                 const u16* __restrict__ Wh,
                                                 const u16* __restrict__ Wl,
                                                 const float* __restrict__ bout,
                                                 float* __restrict__ out) {
  int bid = blockIdx.x;  // 128 = 8 mt x 16 nt
  int mt = bid & 7, nt = bid >> 3;
  int lane = threadIdx.x;
  int l15 = lane & 15, l4 = lane >> 4;
  f32x4 zero = {0.f, 0.f, 0.f, 0.f};
  f32x4 acc0 = zero, acc1 = zero;
  const u16* a0p = h3 + (size_t)(mt * 32 + l15) * NH + l4 * 8;
  const u16* a1p = a0p + 16 * NH;
  const u16* bhp = Wh + (size_t)(nt * 16 + l15) * NH + l4 * 8;
  const u16* blp = Wl + (size_t)(nt * 16 + l15) * NH + l4 * 8;
  for (int kb = 0; kb < 64; kb++) {
    bf16x8 a0 = ld_frag(a0p + kb * 32);
    bf16x8 a1 = ld_frag(a1p + kb * 32);
    bf16x8 bh = ld_frag(bhp + kb * 32);
    bf16x8 bl = ld_frag(blp + kb * 32);
    acc0 = mfma16(a0, bh, acc0);
    acc0 = mfma16(a0, bl, acc0);
    acc1 = mfma16(a1, bh, acc1);
    acc1 = mfma16(a1, bl, acc1);
  }
  float bo = bout[nt * 16 + l15];
  #pragma unroll
  for (int r = 0; r < 4; r++) {
    out[(size_t)(mt * 32 + l4 * 4 + r) * NOUT + nt * 16 + l15] = acc0[r] + bo;
    out[(size_t)(mt * 32 + 16 + l4 * 4 + r) * NOUT + nt * 16 + l15] = acc1[r] + bo;
  }
}

// ---------------- host ----------------

extern "C" void kernel_launch(void* const* d_in, const int* in_sizes, int n_in,
                              void* d_out, int out_size, void* d_ws, size_t ws_size,
                              hipStream_t stream) {
  const float* X     = (const float*)d_in[0];
  const float* Winw  = (const float*)d_in[1];
  const float* Winb  = (const float*)d_in[2];
  const float* Wrw   = (const float*)d_in[3];
  const float* Wrb   = (const float*)d_in[4];
  const float* Woutw = (const float*)d_in[5];
  const float* Woutb = (const float*)d_in[6];
  float* out = (float*)d_out;

  char* ws = (char*)d_ws;
  u8*  W8     = (u8*)(ws);                     // 16 MB  i8 W_rec
  u8*  h0i    = (u8*)(ws + 16777216);          // 2 MB   i8 h
  u8*  h1i    = (u8*)(ws + 18874368);          // 2 MB   i8 h
  u16* h3bf   = (u16*)(ws + 20971520);         // 1 MB   bf16 h layer-3
  float* xin  = (float*)(ws + 22020096);       // 2 MB
  float* Gp2  = (float*)(ws + 24117248);       // 12 MB  fp32 (2 ks x 3 terms)
  u16* Xhi    = (u16*)(ws + 36700160);         // 512 KB
  u16* Xlo    = (u16*)(ws + 37224448);         // 512 KB
  u16* Winh   = (u16*)(ws + 37748736);         // 4 MB
  u16* Winl   = (u16*)(ws + 41943040);         // 4 MB
  u16* Wouth  = (u16*)(ws + 46137344);         // 1 MB
  u16* Woutl  = (u16*)(ws + 47185920);         // 1 MB -> end 48234496

  // pack weights (every call; stateless)
  k_cvt_w8<<<16384, 256, 0, stream>>>(Wrw, (u32*)W8, 4194304);
  k_split2<<<256, 256, 0, stream>>>(X, Xhi, Xlo, 65536);
  k_split2<<<2048, 256, 0, stream>>>(Winw, Winh, Winl, 524288);
  k_split2<<<512, 256, 0, stream>>>(Woutw, Wouth, Woutl, 131072);
  hipMemsetAsync(h0i, 0, 2097152, stream);

  // x_in = X @ W_in^T (+bias), 3-term bf16 split, fp32 partials, split-K 2
  GemmArgs ax;
  ax.A[0] = Xhi; ax.A[1] = Xhi; ax.A[2] = Xlo; ax.A[3] = Xhi;
  ax.B[0] = Winh; ax.B[1] = Winl; ax.B[2] = Winh; ax.B[3] = Winh;
  ax.G = Gp2; ax.ldA = NIN; ax.ldB = NIN; ax.kiters = 8; ax.nl = 3;
  k_gemm<0, 2><<<192, 256, 0, stream>>>(ax);
  k_xin_fin<<<512, 256, 0, stream>>>(Gp2, Winb, xin);

  u8* hin = h0i;
  u8* hout = h1i;
  for (int t = 0; t < TSS; t++) {
    StepArgs ar;
    ar.hin = hin; ar.W8 = W8; ar.hout = hout; ar.h3bf = h3bf;
    ar.xin = xin; ar.brec = Wrb;
    k_step<<<256, 256, 0, stream>>>(ar);
    u8* tmp = hin; hin = hout; hout = tmp;
  }

  // h3bf holds the final layer-3 hidden state (written by last k_step)
  k_gemm_out<<<128, 64, 0, stream>>>(h3bf, Wouth, Woutl, Woutb, out);
}

// Round 17
// 571.323 us; speedup vs baseline: 1.1431x; 1.1431x over previous
//
#include <hip/hip_runtime.h>

typedef unsigned short u16;
typedef unsigned char u8;
typedef unsigned int u32;
typedef __bf16 bf16x8 __attribute__((ext_vector_type(8)));
typedef float f32x4 __attribute__((ext_vector_type(4)));
typedef u32 u32x4 __attribute__((ext_vector_type(4)));
typedef u32 u32x2 __attribute__((ext_vector_type(2)));
typedef u16 u16x4 __attribute__((ext_vector_type(4)));
typedef u16 u16x8 __attribute__((ext_vector_type(8)));
typedef int i32x4 __attribute__((ext_vector_type(4)));

#define NH 2048
#define BATCH 256
#define NIN 1024
#define NOUT 256
#define LAY 4
#define TSS 32
#define BK 64

#define SW_W 5747.0f  // 127 / (1/sqrt(2048)); |W|<0.0220971 -> |W*SW_W|<127.002
#define INV_DQ (1.0f / (127.0f * 5747.0f))

#define WAITVM(N) asm volatile("s_waitcnt vmcnt(" #N ")" ::: "memory")

__device__ __forceinline__ u16 f2bf(float f) {
  u32 u = __builtin_bit_cast(u32, f);
  u = (u + 0x7FFFu + ((u >> 16) & 1u)) >> 16;
  return (u16)u;
}
__device__ __forceinline__ float bf2f(u16 h) {
  u32 u = ((u32)h) << 16;
  return __builtin_bit_cast(float, u);
}

// sin for |x| <= ~6, abs err < ~4e-6 (degree-9 odd, pi range reduction)
__device__ __forceinline__ float fast_sin(float x) {
  float k = __builtin_rintf(x * 0.3183098861837907f);
  float r = __builtin_fmaf(k, -3.14159274101257324f, x);
  r = __builtin_fmaf(k, 8.742277657347586e-08f, r);
  float s = r * r;
  float p = __builtin_fmaf(s, 2.75573192e-06f, -1.98412698e-04f);
  p = __builtin_fmaf(s, p, 8.33333333e-03f);
  p = __builtin_fmaf(s, p, -1.66666667e-01f);
  p = r + r * s * p;
  int ki = (int)k;
  return (ki & 1) ? -p : p;
}

__device__ __forceinline__ bf16x8 ld_frag(const u16* p) {
  u32x4 r = *(const u32x4*)p;
  return __builtin_bit_cast(bf16x8, r);
}

__device__ __forceinline__ f32x4 mfma16(bf16x8 a, bf16x8 b, f32x4 c) {
  return __builtin_amdgcn_mfma_f32_16x16x32_bf16(a, b, c, 0, 0, 0);
}

// i8 MFMA via the documented gfx950 builtin (compiler handles all hazards)
__device__ __forceinline__ i32x4 mfma_i8(i32x4 a, i32x4 b, i32x4 c) {
  return __builtin_amdgcn_mfma_i32_16x16x64_i8(a, b, c, 0, 0, 0);
}

__device__ __forceinline__ void gload16(const void* g, void* lds) {
  __builtin_amdgcn_global_load_lds(
      (__attribute__((address_space(1))) u32*)g,
      (__attribute__((address_space(3))) u32*)lds, 16, 0, 0);
}

// ---------------- fused pack kernel (block-range dispatch) ------------------
// [0,16384): W fp32 -> i8 (4 elems/thread)
// [16384,16640): X split hi/lo (n4=65536)
// [16640,18688): W_in split (n4=524288)
// [18688,19200): W_out split (n4=131072)

struct PackArgs {
  const float* Wrw;
  u32* W8;
  const float* X;
  u16 *Xhi, *Xlo;
  const float* Winw;
  u16 *Winh, *Winl;
  const float* Woutw;
  u16 *Wouth, *Woutl;
};

__device__ __forceinline__ void split4(const float* in, u16* hi, u16* lo,
                                       int i) {
  f32x4 v = ((const f32x4*)in)[i];
  u16x4 hv, lv;
  #pragma unroll
  for (int j = 0; j < 4; j++) {
    u16 h = f2bf(v[j]);
    hv[j] = h;
    lv[j] = f2bf(v[j] - bf2f(h));
  }
  ((u16x4*)hi)[i] = hv;
  ((u16x4*)lo)[i] = lv;
}

__global__ __launch_bounds__(256) void k_pack(PackArgs a) {
  int bid = blockIdx.x;
  int tid = threadIdx.x;
  if (bid < 16384) {
    int i = bid * 256 + tid;
    f32x4 v = ((const f32x4*)a.Wrw)[i];
    u32 o = 0;
    #pragma unroll
    for (int j = 0; j < 4; j++) {
      int q = (int)__builtin_rintf(v[j] * SW_W);
      o |= ((u32)(q & 255)) << (8 * j);
    }
    a.W8[i] = o;
  } else if (bid < 16640) {
    split4(a.X, a.Xhi, a.Xlo, (bid - 16384) * 256 + tid);
  } else if (bid < 18688) {
    split4(a.Winw, a.Winh, a.Winl, (bid - 16640) * 256 + tid);
  } else {
    split4(a.Woutw, a.Wouth, a.Woutl, (bid - 18688) * 256 + tid);
  }
}

// ---------------- bf16 GEMM (r5-proven 2-phase structure; x_in path) --------

struct GemmArgs {
  const u16* A[4];
  const u16* B[4];
  void* G;
  int ldA, ldB, kiters, nl;
};

template <int OBF, int NKS>
__global__ __launch_bounds__(256, 2) void k_gemm(GemmArgs args) {
  __shared__ alignas(16) u16 Ab[2][128 * BK];
  __shared__ alignas(16) u16 Bb[2][128 * BK];

  int bid = blockIdx.x;
  int nl = args.nl;
  int l = bid % nl;
  int t1 = bid / nl;
  int ks = t1 & (NKS - 1);
  int t2 = t1 / NKS;
  int nt = t2 & 15;
  int mt = t2 >> 4;

  int tid = threadIdx.x;
  int w = tid >> 6, lane = tid & 63;
  int l15 = lane & 15, l4 = lane >> 4;
  int ldA = args.ldA, ldB = args.ldB;
  int kiters = args.kiters;

  const u16* Ag = args.A[l] + (size_t)(mt * 128) * ldA + ks * (kiters * BK);
  const u16* Bg = args.B[l] + (size_t)(nt * 128) * ldB + ks * (kiters * BK);

  int srow = w * 32 + (lane >> 3);
  int csrc = ((lane & 7) ^ (lane >> 3)) * 8;
  int agoff[4], bgoff[4], lbase[4];
  #pragma unroll
  for (int j = 0; j < 4; j++) {
    agoff[j] = (srow + j * 8) * ldA + csrc;
    bgoff[j] = (srow + j * 8) * ldB + csrc;
    lbase[j] = w * 2048 + j * 512;
  }

  int wr = w >> 1, wc = w & 1;

  f32x4 zero = {0.f, 0.f, 0.f, 0.f};
  f32x4 acc[4][4];
  #pragma unroll
  for (int m = 0; m < 4; m++)
    #pragma unroll
    for (int n = 0; n < 4; n++) acc[m][n] = zero;

  auto stage = [&](int bufi, int kb) {
    int k0 = kb * BK;
    #pragma unroll
    for (int j = 0; j < 4; j++) {
      gload16(Ag + agoff[j] + k0, &Ab[bufi][lbase[j]]);
      gload16(Bg + bgoff[j] + k0, &Bb[bufi][lbase[j]]);
    }
  };
  auto compute = [&](int bufi) {
    #pragma unroll
    for (int kk = 0; kk < 2; kk++) {
      int swz = ((kk * 4 + l4) ^ (l15 & 7)) * 8;
      bf16x8 a[4], b[4];
      #pragma unroll
      for (int m = 0; m < 4; m++)
        a[m] = ld_frag(&Ab[bufi][(wr * 64 + m * 16 + l15) * BK + swz]);
      #pragma unroll
      for (int n = 0; n < 4; n++)
        b[n] = ld_frag(&Bb[bufi][(wc * 64 + n * 16 + l15) * BK + swz]);
      #pragma unroll
      for (int m = 0; m < 4; m++)
        #pragma unroll
        for (int n = 0; n < 4; n++)
          acc[m][n] = mfma16(a[m], b[n], acc[m][n]);
    }
  };

  stage(0, 0);
  stage(1, 1);

  int cur = 0;
  for (int kb = 0; kb < kiters - 2; kb++) {
    WAITVM(8);
    __builtin_amdgcn_s_barrier();
    compute(cur);
    __builtin_amdgcn_s_barrier();
    stage(cur, kb + 2);
    cur ^= 1;
  }
  WAITVM(8);
  __builtin_amdgcn_s_barrier();
  compute(cur);
  cur ^= 1;
  WAITVM(0);
  __builtin_amdgcn_s_barrier();
  compute(cur);

  size_t obase = ((size_t)(ks * nl + l) * BATCH + mt * 128) * NH + nt * 128;
  if (OBF) {
    u16* Go = (u16*)args.G + obase;
    #pragma unroll
    for (int m = 0; m < 4; m++) {
      int row = wr * 64 + m * 16 + l4 * 4;
      #pragma unroll
      for (int n = 0; n < 4; n++) {
        int col = wc * 64 + n * 16 + l15;
        #pragma unroll
        for (int r = 0; r < 4; r++)
          Go[(size_t)(row + r) * NH + col] = f2bf(acc[m][n][r]);
      }
    }
  } else {
    float* Go = (float*)args.G + obase;
    #pragma unroll
    for (int m = 0; m < 4; m++) {
      int row = wr * 64 + m * 16 + l4 * 4;
      #pragma unroll
      for (int n = 0; n < 4; n++) {
        int col = wc * 64 + n * 16 + l15;
        #pragma unroll
        for (int r = 0; r < 4; r++)
          Go[(size_t)(row + r) * NH + col] = acc[m][n][r];
      }
    }
  }
}

// ---------------- recurrent GEMM, int8: 64x128 tile, full K=2048 (r15) ------
// kiters=16, grid 256 = l(4) x mt(4, 64-row tiles) x nt(16). G is one
// full-sum bf16 slab per layer (4 MB); dequant rounds once.
// 6 gloads/buffer (A:2, B:4) -> WAITVM(6). Wave tile 32x64, acc[2][4].
// Decode: l=bid&3, mt=(bid>>2)&3, nt=bid>>4.

struct Rec8Args {
  const u8* h;    // [LAY][BATCH][NH] i8
  const u8* W8;   // [LAY][NH][NH] i8
  u16* Gp;        // 4 slabs [l][BATCH][NH] bf16
};

__global__ __launch_bounds__(256, 2) void k_gemm8(Rec8Args args) {
  __shared__ alignas(16) u8 Ab[2][64 * 128];   // 8 KB each
  __shared__ alignas(16) u8 Bb[2][128 * 128];  // 16 KB each

  int bid = blockIdx.x;
  int l = bid & 3;
  int mt = (bid >> 2) & 3;
  int nt = bid >> 4;

  int tid = threadIdx.x;
  int lane = tid & 63;
  int w = tid >> 6;
  int l15 = lane & 15, l4 = lane >> 4;
  int wr = w >> 1, wc = w & 1;  // wave tile 32x64

  const u8* Ag = args.h + (size_t)l * (BATCH * NH) + (size_t)(mt * 64) * NH;
  const u8* Bg = args.W8 + (size_t)l * (NH * NH) + (size_t)(nt * 128) * NH;

  int srow = tid >> 3;
  int csrc = ((tid & 7) ^ (srow & 7)) * 16;  // bytes
  int goffA[2], lbaseA[2], goffB[4], lbaseB[4];
  #pragma unroll
  for (int j = 0; j < 2; j++) {
    goffA[j] = (j * 32 + srow) * NH + csrc;
    lbaseA[j] = j * 4096 + tid * 16;
  }
  #pragma unroll
  for (int j = 0; j < 4; j++) {
    goffB[j] = (j * 32 + srow) * NH + csrc;
    lbaseB[j] = j * 4096 + tid * 16;
  }

  i32x4 zero = {0, 0, 0, 0};
  i32x4 acc[2][4];
  #pragma unroll
  for (int m = 0; m < 2; m++)
    #pragma unroll
    for (int n = 0; n < 4; n++) acc[m][n] = zero;

  auto stage = [&](int bufi, int kb) {
    int k0 = kb * 128;
    #pragma unroll
    for (int j = 0; j < 2; j++)
      gload16(Ag + goffA[j] + k0, &Ab[bufi][lbaseA[j]]);
    #pragma unroll
    for (int j = 0; j < 4; j++)
      gload16(Bg + goffB[j] + k0, &Bb[bufi][lbaseB[j]]);
  };
  auto compute = [&](int bufi) {
    #pragma unroll
    for (int kk = 0; kk < 2; kk++) {
      int swz = ((kk * 4 + l4) ^ (l15 & 7)) * 16;  // bytes
      i32x4 a[2], b[4];
      #pragma unroll
      for (int m = 0; m < 2; m++)
        a[m] = *(const i32x4*)&Ab[bufi][(wr * 32 + m * 16 + l15) * 128 + swz];
      #pragma unroll
      for (int n = 0; n < 4; n++)
        b[n] = *(const i32x4*)&Bb[bufi][(wc * 64 + n * 16 + l15) * 128 + swz];
      #pragma unroll
      for (int m = 0; m < 2; m++)
        #pragma unroll
        for (int n = 0; n < 4; n++)
          acc[m][n] = mfma_i8(a[m], b[n], acc[m][n]);
    }
  };

  stage(0, 0);
  stage(1, 1);

  int cur = 0;
  #pragma unroll 1
  for (int kb = 0; kb < 14; kb++) {  // kiters = 16
    WAITVM(6);
    __builtin_amdgcn_s_barrier();
    compute(cur);
    __builtin_amdgcn_s_barrier();
    stage(cur, kb + 2);
    cur ^= 1;
  }
  WAITVM(6);
  __builtin_amdgcn_s_barrier();
  compute(cur);
  cur ^= 1;
  WAITVM(0);
  __builtin_amdgcn_s_barrier();
  compute(cur);

  u16* Go = args.Gp + (size_t)l * (BATCH * NH) + (size_t)(mt * 64) * NH +
            nt * 128;
  #pragma unroll
  for (int m = 0; m < 2; m++) {
    int row = wr * 32 + m * 16 + l4 * 4;
    #pragma unroll
    for (int n = 0; n < 4; n++) {
      int col = wc * 64 + n * 16 + l15;
      #pragma unroll
      for (int r = 0; r < 4; r++)
        Go[(size_t)(row + r) * NH + col] = f2bf((float)acc[m][n][r] * INV_DQ);
    }
  }
}

// ---------------- sin chain (r15-proven; FIRST=1 skips G: h=0 -> G==0) ------
template <int FIRST>
__global__ __launch_bounds__(256) void k_chain8(const u16* __restrict__ Gp,
                                                const float* __restrict__ x_in,
                                                const float* __restrict__ brec,
                                                u8* __restrict__ hq,
                                                u16* __restrict__ h3bf) {
  int i = blockIdx.x * 256 + threadIdx.x;  // 65536 threads, 8 elems each
  int e = i * 8;
  int col = e & (NH - 1);
  f32x4 p0 = *(const f32x4*)(x_in + e);
  f32x4 p1 = *(const f32x4*)(x_in + e + 4);
  #pragma unroll
  for (int l = 0; l < LAY; l++) {
    u16x8 g0;
    if (FIRST) {
      #pragma unroll
      for (int j = 0; j < 8; j++) g0[j] = 0;
    } else {
      g0 = *(const u16x8*)(Gp + (size_t)l * (BATCH * NH) + e);
    }
    f32x4 b0 = *(const f32x4*)(brec + l * NH + col);
    f32x4 b1 = *(const f32x4*)(brec + l * NH + col + 4);
    u32x2 qw = {0u, 0u};
    u16x8 hv;
    #pragma unroll
    for (int j = 0; j < 4; j++) {
      float v = fast_sin(p0[j] + bf2f(g0[j]) + b0[j]);
      p0[j] = v;
      int q = (int)__builtin_rintf(v * 127.0f);
      qw[0] |= ((u32)(q & 255)) << (8 * j);
      hv[j] = f2bf(v);
    }
    #pragma unroll
    for (int j = 0; j < 4; j++) {
      float v = fast_sin(p1[j] + bf2f(g0[4 + j]) + b1[j]);
      p1[j] = v;
      int q = (int)__builtin_rintf(v * 127.0f);
      qw[1] |= ((u32)(q & 255)) << (8 * j);
      hv[4 + j] = f2bf(v);
    }
    *(u32x2*)(hq + (size_t)l * (BATCH * NH) + e) = qw;
    if (l == LAY - 1) *(u16x8*)(h3bf + e) = hv;
  }
}

// x_in = sum of 6 partial slices + bias (fp32 partials)
__global__ __launch_bounds__(256) void k_xin_fin(const float* __restrict__ Gp2,
                                                 const float* __restrict__ bin,
                                                 float* __restrict__ x_in) {
  int i = blockIdx.x * 256 + threadIdx.x;
  int e = i * 4;
  int col = e & (NH - 1);
  f32x4 s = *(const f32x4*)(bin + col);
  #pragma unroll
  for (int t = 0; t < 6; t++)
    s += *(const f32x4*)(Gp2 + (size_t)t * (BATCH * NH) + e);
  *(f32x4*)(x_in + e) = s;
}

// ---------------- output projection: out = h3 @ (Wh+Wl)^T + b ----------------
__global__ __launch_bounds__(64) void k_gemm_out(const u16* __restrict__ h3,
                                                 const u16* __restrict__ Wh,
                                                 const u16* __restrict__ Wl,
                                                 const float* __restrict__ bout,
                                                 float* __restrict__ out) {
  int bid = blockIdx.x;  // 128 = 8 mt x 16 nt
  int mt = bid & 7, nt = bid >> 3;
  int lane = threadIdx.x;
  int l15 = lane & 15, l4 = lane >> 4;
  f32x4 zero = {0.f, 0.f, 0.f, 0.f};
  f32x4 acc0 = zero, acc1 = zero;
  const u16* a0p = h3 + (size_t)(mt * 32 + l15) * NH + l4 * 8;
  const u16* a1p = a0p + 16 * NH;
  const u16* bhp = Wh + (size_t)(nt * 16 + l15) * NH + l4 * 8;
  const u16* blp = Wl + (size_t)(nt * 16 + l15) * NH + l4 * 8;
  for (int kb = 0; kb < 64; kb++) {
    bf16x8 a0 = ld_frag(a0p + kb * 32);
    bf16x8 a1 = ld_frag(a1p + kb * 32);
    bf16x8 bh = ld_frag(bhp + kb * 32);
    bf16x8 bl = ld_frag(blp + kb * 32);
    acc0 = mfma16(a0, bh, acc0);
    acc0 = mfma16(a0, bl, acc0);
    acc1 = mfma16(a1, bh, acc1);
    acc1 = mfma16(a1, bl, acc1);
  }
  float bo = bout[nt * 16 + l15];
  #pragma unroll
  for (int r = 0; r < 4; r++) {
    out[(size_t)(mt * 32 + l4 * 4 + r) * NOUT + nt * 16 + l15] = acc0[r] + bo;
    out[(size_t)(mt * 32 + 16 + l4 * 4 + r) * NOUT + nt * 16 + l15] = acc1[r] + bo;
  }
}

// ---------------- host ----------------

extern "C" void kernel_launch(void* const* d_in, const int* in_sizes, int n_in,
                              void* d_out, int out_size, void* d_ws, size_t ws_size,
                              hipStream_t stream) {
  const float* X     = (const float*)d_in[0];
  const float* Winw  = (const float*)d_in[1];
  const float* Winb  = (const float*)d_in[2];
  const float* Wrw   = (const float*)d_in[3];
  const float* Wrb   = (const float*)d_in[4];
  const float* Woutw = (const float*)d_in[5];
  const float* Woutb = (const float*)d_in[6];
  float* out = (float*)d_out;

  char* ws = (char*)d_ws;
  u8*  W8     = (u8*)(ws);                     // 16 MB  i8 W_rec
  u8*  h0i    = (u8*)(ws + 16777216);          // 2 MB   i8 h
  u8*  h1i    = (u8*)(ws + 18874368);          // 2 MB   i8 h
  u16* h3bf   = (u16*)(ws + 20971520);         // 1 MB   bf16 h layer-3
  float* xin  = (float*)(ws + 22020096);       // 2 MB
  u16* Gp     = (u16*)(ws + 24117248);         // 4 MB   bf16 (4 l)
  float* Gp2  = (float*)(ws + 28311552);       // 12 MB  fp32 (2 ks x 3 terms)
  u16* Xhi    = (u16*)(ws + 40894464);         // 512 KB
  u16* Xlo    = (u16*)(ws + 41418752);         // 512 KB
  u16* Winh   = (u16*)(ws + 41943040);         // 4 MB
  u16* Winl   = (u16*)(ws + 46137344);         // 4 MB
  u16* Wouth  = (u16*)(ws + 50331648);         // 1 MB
  u16* Woutl  = (u16*)(ws + 51380224);         // 1 MB -> end 52428800

  // fused pack (every call; stateless; bit-identical to r15's 4 kernels)
  PackArgs pa;
  pa.Wrw = Wrw; pa.W8 = (u32*)W8;
  pa.X = X; pa.Xhi = Xhi; pa.Xlo = Xlo;
  pa.Winw = Winw; pa.Winh = Winh; pa.Winl = Winl;
  pa.Woutw = Woutw; pa.Wouth = Wouth; pa.Woutl = Woutl;
  k_pack<<<19200, 256, 0, stream>>>(pa);

  // x_in = X @ W_in^T (+bias), 3-term bf16 split, fp32 partials, split-K 2
  GemmArgs ax;
  ax.A[0] = Xhi; ax.A[1] = Xhi; ax.A[2] = Xlo; ax.A[3] = Xhi;
  ax.B[0] = Winh; ax.B[1] = Winl; ax.B[2] = Winh; ax.B[3] = Winh;
  ax.G = Gp2; ax.ldA = NIN; ax.ldB = NIN; ax.kiters = 8; ax.nl = 3;
  k_gemm<0, 2><<<192, 256, 0, stream>>>(ax);
  k_xin_fin<<<512, 256, 0, stream>>>(Gp2, Winb, xin);

  // t = 0: h = 0 -> G == 0 exactly; chain only (bit-identical to r15's t=0)
  k_chain8<1><<<256, 256, 0, stream>>>(Gp, xin, Wrb, h1i, h3bf);

  u8* hin = h1i;
  u8* hout = h0i;
  for (int t = 1; t < TSS; t++) {
    Rec8Args ar;
    ar.h = hin; ar.W8 = W8; ar.Gp = Gp;
    k_gemm8<<<256, 256, 0, stream>>>(ar);
    k_chain8<0><<<256, 256, 0, stream>>>(Gp, xin, Wrb, hout, h3bf);
    u8* tmp = hin; hin = hout; hout = tmp;
  }

  // h3bf holds the final layer-3 hidden state (written by last k_chain8)
  k_gemm_out<<<128, 64, 0, stream>>>(h3bf, Wouth, Woutl, Woutb, out);
}

// Round 18
// 568.035 us; speedup vs baseline: 1.1497x; 1.0058x over previous
//
#include <hip/hip_runtime.h>

typedef unsigned short u16;
typedef unsigned char u8;
typedef unsigned int u32;
typedef __bf16 bf16x8 __attribute__((ext_vector_type(8)));
typedef float f32x4 __attribute__((ext_vector_type(4)));
typedef u32 u32x4 __attribute__((ext_vector_type(4)));
typedef u32 u32x2 __attribute__((ext_vector_type(2)));
typedef u16 u16x4 __attribute__((ext_vector_type(4)));
typedef u16 u16x8 __attribute__((ext_vector_type(8)));
typedef int i32x4 __attribute__((ext_vector_type(4)));

#define NH 2048
#define BATCH 256
#define NIN 1024
#define NOUT 256
#define LAY 4
#define TSS 32
#define BK 64

#define SW_W 5747.0f  // 127 / (1/sqrt(2048)); |W|<0.0220971 -> |W*SW_W|<127.002
#define INV_DQ (1.0f / (127.0f * 5747.0f))

#define WAITVM(N) asm volatile("s_waitcnt vmcnt(" #N ")" ::: "memory")

__device__ __forceinline__ u16 f2bf(float f) {
  u32 u = __builtin_bit_cast(u32, f);
  u = (u + 0x7FFFu + ((u >> 16) & 1u)) >> 16;
  return (u16)u;
}
__device__ __forceinline__ float bf2f(u16 h) {
  u32 u = ((u32)h) << 16;
  return __builtin_bit_cast(float, u);
}

// sin for |x| <= ~6, abs err < ~4e-6 (degree-9 odd, pi range reduction)
__device__ __forceinline__ float fast_sin(float x) {
  float k = __builtin_rintf(x * 0.3183098861837907f);
  float r = __builtin_fmaf(k, -3.14159274101257324f, x);
  r = __builtin_fmaf(k, 8.742277657347586e-08f, r);
  float s = r * r;
  float p = __builtin_fmaf(s, 2.75573192e-06f, -1.98412698e-04f);
  p = __builtin_fmaf(s, p, 8.33333333e-03f);
  p = __builtin_fmaf(s, p, -1.66666667e-01f);
  p = r + r * s * p;
  int ki = (int)k;
  return (ki & 1) ? -p : p;
}

__device__ __forceinline__ bf16x8 ld_frag(const u16* p) {
  u32x4 r = *(const u32x4*)p;
  return __builtin_bit_cast(bf16x8, r);
}

__device__ __forceinline__ f32x4 mfma16(bf16x8 a, bf16x8 b, f32x4 c) {
  return __builtin_amdgcn_mfma_f32_16x16x32_bf16(a, b, c, 0, 0, 0);
}

// i8 MFMA via the documented gfx950 builtin (compiler handles all hazards)
__device__ __forceinline__ i32x4 mfma_i8(i32x4 a, i32x4 b, i32x4 c) {
  return __builtin_amdgcn_mfma_i32_16x16x64_i8(a, b, c, 0, 0, 0);
}

__device__ __forceinline__ void gload16(const void* g, void* lds) {
  __builtin_amdgcn_global_load_lds(
      (__attribute__((address_space(1))) u32*)g,
      (__attribute__((address_space(3))) u32*)lds, 16, 0, 0);
}

// ---------------- fused pack kernel (block-range dispatch) ------------------
// [0,16384): W fp32 -> i8 (4 elems/thread)
// [16384,16640): X split hi/lo (n4=65536)
// [16640,18688): W_in split (n4=524288)
// [18688,19200): W_out split (n4=131072)

struct PackArgs {
  const float* Wrw;
  u32* W8;
  const float* X;
  u16 *Xhi, *Xlo;
  const float* Winw;
  u16 *Winh, *Winl;
  const float* Woutw;
  u16 *Wouth, *Woutl;
};

__device__ __forceinline__ void split4(const float* in, u16* hi, u16* lo,
                                       int i) {
  f32x4 v = ((const f32x4*)in)[i];
  u16x4 hv, lv;
  #pragma unroll
  for (int j = 0; j < 4; j++) {
    u16 h = f2bf(v[j]);
    hv[j] = h;
    lv[j] = f2bf(v[j] - bf2f(h));
  }
  ((u16x4*)hi)[i] = hv;
  ((u16x4*)lo)[i] = lv;
}

__global__ __launch_bounds__(256) void k_pack(PackArgs a) {
  int bid = blockIdx.x;
  int tid = threadIdx.x;
  if (bid < 16384) {
    int i = bid * 256 + tid;
    f32x4 v = ((const f32x4*)a.Wrw)[i];
    u32 o = 0;
    #pragma unroll
    for (int j = 0; j < 4; j++) {
      int q = (int)__builtin_rintf(v[j] * SW_W);
      o |= ((u32)(q & 255)) << (8 * j);
    }
    a.W8[i] = o;
  } else if (bid < 16640) {
    split4(a.X, a.Xhi, a.Xlo, (bid - 16384) * 256 + tid);
  } else if (bid < 18688) {
    split4(a.Winw, a.Winh, a.Winl, (bid - 16640) * 256 + tid);
  } else {
    split4(a.Woutw, a.Wouth, a.Woutl, (bid - 18688) * 256 + tid);
  }
}

// ---------------- bf16 GEMM (r5-proven 2-phase structure; x_in path) --------

struct GemmArgs {
  const u16* A[4];
  const u16* B[4];
  void* G;
  int ldA, ldB, kiters, nl;
};

template <int OBF, int NKS>
__global__ __launch_bounds__(256, 2) void k_gemm(GemmArgs args) {
  __shared__ alignas(16) u16 Ab[2][128 * BK];
  __shared__ alignas(16) u16 Bb[2][128 * BK];

  int bid = blockIdx.x;
  int nl = args.nl;
  int l = bid % nl;
  int t1 = bid / nl;
  int ks = t1 & (NKS - 1);
  int t2 = t1 / NKS;
  int nt = t2 & 15;
  int mt = t2 >> 4;

  int tid = threadIdx.x;
  int w = tid >> 6, lane = tid & 63;
  int l15 = lane & 15, l4 = lane >> 4;
  int ldA = args.ldA, ldB = args.ldB;
  int kiters = args.kiters;

  const u16* Ag = args.A[l] + (size_t)(mt * 128) * ldA + ks * (kiters * BK);
  const u16* Bg = args.B[l] + (size_t)(nt * 128) * ldB + ks * (kiters * BK);

  int srow = w * 32 + (lane >> 3);
  int csrc = ((lane & 7) ^ (lane >> 3)) * 8;
  int agoff[4], bgoff[4], lbase[4];
  #pragma unroll
  for (int j = 0; j < 4; j++) {
    agoff[j] = (srow + j * 8) * ldA + csrc;
    bgoff[j] = (srow + j * 8) * ldB + csrc;
    lbase[j] = w * 2048 + j * 512;
  }

  int wr = w >> 1, wc = w & 1;

  f32x4 zero = {0.f, 0.f, 0.f, 0.f};
  f32x4 acc[4][4];
  #pragma unroll
  for (int m = 0; m < 4; m++)
    #pragma unroll
    for (int n = 0; n < 4; n++) acc[m][n] = zero;

  auto stage = [&](int bufi, int kb) {
    int k0 = kb * BK;
    #pragma unroll
    for (int j = 0; j < 4; j++) {
      gload16(Ag + agoff[j] + k0, &Ab[bufi][lbase[j]]);
      gload16(Bg + bgoff[j] + k0, &Bb[bufi][lbase[j]]);
    }
  };
  auto compute = [&](int bufi) {
    #pragma unroll
    for (int kk = 0; kk < 2; kk++) {
      int swz = ((kk * 4 + l4) ^ (l15 & 7)) * 8;
      bf16x8 a[4], b[4];
      #pragma unroll
      for (int m = 0; m < 4; m++)
        a[m] = ld_frag(&Ab[bufi][(wr * 64 + m * 16 + l15) * BK + swz]);
      #pragma unroll
      for (int n = 0; n < 4; n++)
        b[n] = ld_frag(&Bb[bufi][(wc * 64 + n * 16 + l15) * BK + swz]);
      #pragma unroll
      for (int m = 0; m < 4; m++)
        #pragma unroll
        for (int n = 0; n < 4; n++)
          acc[m][n] = mfma16(a[m], b[n], acc[m][n]);
    }
  };

  stage(0, 0);
  stage(1, 1);

  int cur = 0;
  for (int kb = 0; kb < kiters - 2; kb++) {
    WAITVM(8);
    __builtin_amdgcn_s_barrier();
    compute(cur);
    __builtin_amdgcn_s_barrier();
    stage(cur, kb + 2);
    cur ^= 1;
  }
  WAITVM(8);
  __builtin_amdgcn_s_barrier();
  compute(cur);
  cur ^= 1;
  WAITVM(0);
  __builtin_amdgcn_s_barrier();
  compute(cur);

  size_t obase = ((size_t)(ks * nl + l) * BATCH + mt * 128) * NH + nt * 128;
  if (OBF) {
    u16* Go = (u16*)args.G + obase;
    #pragma unroll
    for (int m = 0; m < 4; m++) {
      int row = wr * 64 + m * 16 + l4 * 4;
      #pragma unroll
      for (int n = 0; n < 4; n++) {
        int col = wc * 64 + n * 16 + l15;
        #pragma unroll
        for (int r = 0; r < 4; r++)
          Go[(size_t)(row + r) * NH + col] = f2bf(acc[m][n][r]);
      }
    }
  } else {
    float* Go = (float*)args.G + obase;
    #pragma unroll
    for (int m = 0; m < 4; m++) {
      int row = wr * 64 + m * 16 + l4 * 4;
      #pragma unroll
      for (int n = 0; n < 4; n++) {
        int col = wc * 64 + n * 16 + l15;
        #pragma unroll
        for (int r = 0; r < 4; r++)
          Go[(size_t)(row + r) * NH + col] = acc[m][n][r];
      }
    }
  }
}

// ---------------- recurrent GEMM, int8: 64x128 tile, K=2048, DEPTH-3 --------
// r15 kernel with the pipeline deepened 2->3 buffers (72 KB LDS, 1 block/CU
// at grid 256): WAITVM(12) waits loads issued TWO compute phases ago (~500
// cyc of cover vs L2/HBM ~500-900) instead of one. Same proven 2-barrier
// schedule (r4's single-barrier failure mode not touched); tail 12->6->0.
// 6 gloads/buffer (A:2, B:4). Wave tile 32x64, acc[2][4].
// Decode: l=bid&3, mt=(bid>>2)&3, nt=bid>>4.

struct Rec8Args {
  const u8* h;    // [LAY][BATCH][NH] i8
  const u8* W8;   // [LAY][NH][NH] i8
  u16* Gp;        // 4 slabs [l][BATCH][NH] bf16
};

__global__ __launch_bounds__(256, 2) void k_gemm8(Rec8Args args) {
  __shared__ alignas(16) u8 Ab[3][64 * 128];   // 8 KB each
  __shared__ alignas(16) u8 Bb[3][128 * 128];  // 16 KB each

  int bid = blockIdx.x;
  int l = bid & 3;
  int mt = (bid >> 2) & 3;
  int nt = bid >> 4;

  int tid = threadIdx.x;
  int lane = tid & 63;
  int w = tid >> 6;
  int l15 = lane & 15, l4 = lane >> 4;
  int wr = w >> 1, wc = w & 1;  // wave tile 32x64

  const u8* Ag = args.h + (size_t)l * (BATCH * NH) + (size_t)(mt * 64) * NH;
  const u8* Bg = args.W8 + (size_t)l * (NH * NH) + (size_t)(nt * 128) * NH;

  int srow = tid >> 3;
  int csrc = ((tid & 7) ^ (srow & 7)) * 16;  // bytes
  int goffA[2], lbaseA[2], goffB[4], lbaseB[4];
  #pragma unroll
  for (int j = 0; j < 2; j++) {
    goffA[j] = (j * 32 + srow) * NH + csrc;
    lbaseA[j] = j * 4096 + tid * 16;
  }
  #pragma unroll
  for (int j = 0; j < 4; j++) {
    goffB[j] = (j * 32 + srow) * NH + csrc;
    lbaseB[j] = j * 4096 + tid * 16;
  }

  i32x4 zero = {0, 0, 0, 0};
  i32x4 acc[2][4];
  #pragma unroll
  for (int m = 0; m < 2; m++)
    #pragma unroll
    for (int n = 0; n < 4; n++) acc[m][n] = zero;

  auto stage = [&](int bufi, int kb) {
    int k0 = kb * 128;
    #pragma unroll
    for (int j = 0; j < 2; j++)
      gload16(Ag + goffA[j] + k0, &Ab[bufi][lbaseA[j]]);
    #pragma unroll
    for (int j = 0; j < 4; j++)
      gload16(Bg + goffB[j] + k0, &Bb[bufi][lbaseB[j]]);
  };
  auto compute = [&](int bufi) {
    #pragma unroll
    for (int kk = 0; kk < 2; kk++) {
      int swz = ((kk * 4 + l4) ^ (l15 & 7)) * 16;  // bytes
      i32x4 a[2], b[4];
      #pragma unroll
      for (int m = 0; m < 2; m++)
        a[m] = *(const i32x4*)&Ab[bufi][(wr * 32 + m * 16 + l15) * 128 + swz];
      #pragma unroll
      for (int n = 0; n < 4; n++)
        b[n] = *(const i32x4*)&Bb[bufi][(wc * 64 + n * 16 + l15) * 128 + swz];
      #pragma unroll
      for (int m = 0; m < 2; m++)
        #pragma unroll
        for (int n = 0; n < 4; n++)
          acc[m][n] = mfma_i8(a[m], b[n], acc[m][n]);
    }
  };

  // prologue: 3 tiles in flight (18 loads/thread-group)
  stage(0, 0);
  stage(1, 1);
  stage(2, 2);

  int cur = 0;
  #pragma unroll 1
  for (int kb = 0; kb < 13; kb++) {  // kiters = 16, depth-3
    WAITVM(12);
    __builtin_amdgcn_s_barrier();
    compute(cur);
    __builtin_amdgcn_s_barrier();
    stage(cur, kb + 3);
    cur = (cur == 2) ? 0 : cur + 1;
  }
  // tail: outstanding 18 -> 12 -> 6 -> 0
  WAITVM(12);
  __builtin_amdgcn_s_barrier();
  compute(cur);
  cur = (cur == 2) ? 0 : cur + 1;
  WAITVM(6);
  __builtin_amdgcn_s_barrier();
  compute(cur);
  cur = (cur == 2) ? 0 : cur + 1;
  WAITVM(0);
  __builtin_amdgcn_s_barrier();
  compute(cur);

  u16* Go = args.Gp + (size_t)l * (BATCH * NH) + (size_t)(mt * 64) * NH +
            nt * 128;
  #pragma unroll
  for (int m = 0; m < 2; m++) {
    int row = wr * 32 + m * 16 + l4 * 4;
    #pragma unroll
    for (int n = 0; n < 4; n++) {
      int col = wc * 64 + n * 16 + l15;
      #pragma unroll
      for (int r = 0; r < 4; r++)
        Go[(size_t)(row + r) * NH + col] = f2bf((float)acc[m][n][r] * INV_DQ);
    }
  }
}

// ---------------- sin chain (MODE: 0=first t=0, 1=mid, 2=last t=31) ---------
// MODE 0: G==0 (h=0), write hq only. MODE 1: read G, write hq only.
// MODE 2: read G, write h3bf only (hq of the last step is never read).
template <int MODE>
__global__ __launch_bounds__(256) void k_chain8(const u16* __restrict__ Gp,
                                                const float* __restrict__ x_in,
                                                const float* __restrict__ brec,
                                                u8* __restrict__ hq,
                                                u16* __restrict__ h3bf) {
  int i = blockIdx.x * 256 + threadIdx.x;  // 65536 threads, 8 elems each
  int e = i * 8;
  int col = e & (NH - 1);
  f32x4 p0 = *(const f32x4*)(x_in + e);
  f32x4 p1 = *(const f32x4*)(x_in + e + 4);
  #pragma unroll
  for (int l = 0; l < LAY; l++) {
    u16x8 g0;
    if (MODE == 0) {
      #pragma unroll
      for (int j = 0; j < 8; j++) g0[j] = 0;
    } else {
      g0 = *(const u16x8*)(Gp + (size_t)l * (BATCH * NH) + e);
    }
    f32x4 b0 = *(const f32x4*)(brec + l * NH + col);
    f32x4 b1 = *(const f32x4*)(brec + l * NH + col + 4);
    u32x2 qw = {0u, 0u};
    u16x8 hv;
    #pragma unroll
    for (int j = 0; j < 4; j++) {
      float v = fast_sin(p0[j] + bf2f(g0[j]) + b0[j]);
      p0[j] = v;
      int q = (int)__builtin_rintf(v * 127.0f);
      qw[0] |= ((u32)(q & 255)) << (8 * j);
      hv[j] = f2bf(v);
    }
    #pragma unroll
    for (int j = 0; j < 4; j++) {
      float v = fast_sin(p1[j] + bf2f(g0[4 + j]) + b1[j]);
      p1[j] = v;
      int q = (int)__builtin_rintf(v * 127.0f);
      qw[1] |= ((u32)(q & 255)) << (8 * j);
      hv[4 + j] = f2bf(v);
    }
    if (MODE != 2) *(u32x2*)(hq + (size_t)l * (BATCH * NH) + e) = qw;
    if (MODE == 2 && l == LAY - 1) *(u16x8*)(h3bf + e) = hv;
  }
}

// x_in = sum of 6 partial slices + bias (fp32 partials)
__global__ __launch_bounds__(256) void k_xin_fin(const float* __restrict__ Gp2,
                                                 const float* __restrict__ bin,
                                                 float* __restrict__ x_in) {
  int i = blockIdx.x * 256 + threadIdx.x;
  int e = i * 4;
  int col = e & (NH - 1);
  f32x4 s = *(const f32x4*)(bin + col);
  #pragma unroll
  for (int t = 0; t < 6; t++)
    s += *(const f32x4*)(Gp2 + (size_t)t * (BATCH * NH) + e);
  *(f32x4*)(x_in + e) = s;
}

// ---------------- output projection: out = h3 @ (Wh+Wl)^T + b ----------------
__global__ __launch_bounds__(64) void k_gemm_out(const u16* __restrict__ h3,
                                                 const u16* __restrict__ Wh,
                                                 const u16* __restrict__ Wl,
                                                 const float* __restrict__ bout,
                                                 float* __restrict__ out) {
  int bid = blockIdx.x;  // 128 = 8 mt x 16 nt
  int mt = bid & 7, nt = bid >> 3;
  int lane = threadIdx.x;
  int l15 = lane & 15, l4 = lane >> 4;
  f32x4 zero = {0.f, 0.f, 0.f, 0.f};
  f32x4 acc0 = zero, acc1 = zero;
  const u16* a0p = h3 + (size_t)(mt * 32 + l15) * NH + l4 * 8;
  const u16* a1p = a0p + 16 * NH;
  const u16* bhp = Wh + (size_t)(nt * 16 + l15) * NH + l4 * 8;
  const u16* blp = Wl + (size_t)(nt * 16 + l15) * NH + l4 * 8;
  for (int kb = 0; kb < 64; kb++) {
    bf16x8 a0 = ld_frag(a0p + kb * 32);
    bf16x8 a1 = ld_frag(a1p + kb * 32);
    bf16x8 bh = ld_frag(bhp + kb * 32);
    bf16x8 bl = ld_frag(blp + kb * 32);
    acc0 = mfma16(a0, bh, acc0);
    acc0 = mfma16(a0, bl, acc0);
    acc1 = mfma16(a1, bh, acc1);
    acc1 = mfma16(a1, bl, acc1);
  }
  float bo = bout[nt * 16 + l15];
  #pragma unroll
  for (int r = 0; r < 4; r++) {
    out[(size_t)(mt * 32 + l4 * 4 + r) * NOUT + nt * 16 + l15] = acc0[r] + bo;
    out[(size_t)(mt * 32 + 16 + l4 * 4 + r) * NOUT + nt * 16 + l15] = acc1[r] + bo;
  }
}

// ---------------- host ----------------

extern "C" void kernel_launch(void* const* d_in, const int* in_sizes, int n_in,
                              void* d_out, int out_size, void* d_ws, size_t ws_size,
                              hipStream_t stream) {
  const float* X     = (const float*)d_in[0];
  const float* Winw  = (const float*)d_in[1];
  const float* Winb  = (const float*)d_in[2];
  const float* Wrw   = (const float*)d_in[3];
  const float* Wrb   = (const float*)d_in[4];
  const float* Woutw = (const float*)d_in[5];
  const float* Woutb = (const float*)d_in[6];
  float* out = (float*)d_out;

  char* ws = (char*)d_ws;
  u8*  W8     = (u8*)(ws);                     // 16 MB  i8 W_rec
  u8*  h0i    = (u8*)(ws + 16777216);          // 2 MB   i8 h
  u8*  h1i    = (u8*)(ws + 18874368);          // 2 MB   i8 h
  u16* h3bf   = (u16*)(ws + 20971520);         // 1 MB   bf16 h layer-3
  float* xin  = (float*)(ws + 22020096);       // 2 MB
  u16* Gp     = (u16*)(ws + 24117248);         // 4 MB   bf16 (4 l)
  float* Gp2  = (float*)(ws + 28311552);       // 12 MB  fp32 (2 ks x 3 terms)
  u16* Xhi    = (u16*)(ws + 40894464);         // 512 KB
  u16* Xlo    = (u16*)(ws + 41418752);         // 512 KB
  u16* Winh   = (u16*)(ws + 41943040);         // 4 MB
  u16* Winl   = (u16*)(ws + 46137344);         // 4 MB
  u16* Wouth  = (u16*)(ws + 50331648);         // 1 MB
  u16* Woutl  = (u16*)(ws + 51380224);         // 1 MB -> end 52428800

  // fused pack (every call; stateless)
  PackArgs pa;
  pa.Wrw = Wrw; pa.W8 = (u32*)W8;
  pa.X = X; pa.Xhi = Xhi; pa.Xlo = Xlo;
  pa.Winw = Winw; pa.Winh = Winh; pa.Winl = Winl;
  pa.Woutw = Woutw; pa.Wouth = Wouth; pa.Woutl = Woutl;
  k_pack<<<19200, 256, 0, stream>>>(pa);

  // x_in = X @ W_in^T (+bias), 3-term bf16 split, fp32 partials, split-K 2
  GemmArgs ax;
  ax.A[0] = Xhi; ax.A[1] = Xhi; ax.A[2] = Xlo; ax.A[3] = Xhi;
  ax.B[0] = Winh; ax.B[1] = Winl; ax.B[2] = Winh; ax.B[3] = Winh;
  ax.G = Gp2; ax.ldA = NIN; ax.ldB = NIN; ax.kiters = 8; ax.nl = 3;
  k_gemm<0, 2><<<192, 256, 0, stream>>>(ax);
  k_xin_fin<<<512, 256, 0, stream>>>(Gp2, Winb, xin);

  // t = 0: h = 0 -> G == 0 exactly; chain only
  k_chain8<0><<<256, 256, 0, stream>>>(Gp, xin, Wrb, h1i, h3bf);

  u8* hin = h1i;
  u8* hout = h0i;
  for (int t = 1; t < TSS; t++) {
    Rec8Args ar;
    ar.h = hin; ar.W8 = W8; ar.Gp = Gp;
    k_gemm8<<<256, 256, 0, stream>>>(ar);
    if (t < TSS - 1)
      k_chain8<1><<<256, 256, 0, stream>>>(Gp, xin, Wrb, hout, h3bf);
    else
      k_chain8<2><<<256, 256, 0, stream>>>(Gp, xin, Wrb, hout, h3bf);
    u8* tmp = hin; hin = hout; hout = tmp;
  }

  // h3bf holds the final layer-3 hidden state (written by last k_chain8)
  k_gemm_out<<<128, 64, 0, stream>>>(h3bf, Wouth, Woutl, Woutb, out);
}